// Round 10
// baseline (342.913 us; speedup 1.0000x reference)
//
#include <hip/hip_runtime.h>
#include <float.h>

typedef _Float16 half8 __attribute__((ext_vector_type(8)));
typedef _Float16 half4v __attribute__((ext_vector_type(4)));
typedef float f32x4 __attribute__((ext_vector_type(4)));

#define M_TOTAL 16384
#define N_CODES 8192
#define KDIM    256
#define BM 128
#define BN 256
#define BK 32
#define NK (KDIM / BK)      // 8 k-iterations
#define NB (N_CODES / BN)   // 32 partials per query
#define TS 32               // LDS tile k-stride in halfs
#define MARGIN 3.6e-3f      // >= 2*(fp16-approx err + 8-bit key truncation)
#define SQ_SCALE 512.0f
#define SE_SCALE 2048.0f
#define INV_PROD 1.9073486328125e-06f   // 2/(512*2048) = 2^-19, exact
#define LR_BLOCKS 32         // loss_reduce grid

// grid split for fused prep kernel
#define PREP_Q_BLOCKS (M_TOTAL / 4)                 // 4096
#define PREP_E_BLOCKS (N_CODES / 4)                 // 2048
#define TR_BLOCKS ((N_CODES / 64) * (KDIM / 64))    // 512

// ---------------------------------------------------------------------------
// prep body: fp32 -> fp16 (exact pow2 scale) + numpy-bit-exact sumsq (r7-r9).
// ---------------------------------------------------------------------------
__device__ __forceinline__ void prep_body(const float* __restrict__ src,
                                          _Float16* __restrict__ dst,
                                          float* __restrict__ sq, float scale,
                                          int row0, int tid) {
    {   // convert
        const int r = row0 + (tid >> 6);
        const int e4 = tid & 63;
        const float4 v = *(const float4*)(src + (size_t)r * KDIM + e4 * 4);
        const half4v h = {(_Float16)(v.x * scale), (_Float16)(v.y * scale),
                          (_Float16)(v.z * scale), (_Float16)(v.w * scale)};
        ((half4v*)(dst + (size_t)r * KDIM))[e4] = h;
    }
    if (tid < 64) {   // np-bit-exact sumsq, 4 rows on wave 0
        const int grp = tid >> 4;
        const int sub = tid & 15;
        const int row = row0 + grp;
        const float* p = src + (size_t)row * KDIM + (sub >> 3) * 128 + (sub & 7);
        float r;
        {
            #pragma clang fp contract(off)
            float v = p[0];
            r = v * v;
            #pragma unroll
            for (int k = 1; k < 16; k++) { const float w = p[k * 8]; r = r + w * w; }
        }
        const float t1 = r  + __shfl_xor(r,  1, 64);
        const float t2 = t1 + __shfl_xor(t1, 2, 64);
        const float t3 = t2 + __shfl_xor(t2, 4, 64);
        const float t4 = t3 + __shfl_xor(t3, 8, 64);
        if (sub == 0) sq[row] = t4;
    }
}

// ---------------------------------------------------------------------------
// Fused prep: prep(Q) + prep(E) + E-transpose in ONE dispatch.
// Block 0 zeroes the loss accumulator (r15: fcount/flist eliminated).
// ---------------------------------------------------------------------------
__global__ void prep_fused_kernel(const float* __restrict__ Q, const float* __restrict__ E,
                                  _Float16* __restrict__ Qh, _Float16* __restrict__ Eh,
                                  float* __restrict__ qsq, float* __restrict__ esq,
                                  float* __restrict__ ET, float* __restrict__ loss_slot) {
    __shared__ float tile[64][65];
    const int tid = threadIdx.x;
    const int b = blockIdx.x;
    if (b == 0 && tid == 0) *loss_slot = 0.f;
    if (b < PREP_Q_BLOCKS) {
        prep_body(Q, Qh, qsq, SQ_SCALE, b * 4, tid);
        return;
    }
    if (b < PREP_Q_BLOCKS + PREP_E_BLOCKS) {
        prep_body(E, Eh, esq, SE_SCALE, (b - PREP_Q_BLOCKS) * 4, tid);
        return;
    }
    // transpose: ET[k][n] = E[n][k], 64x64 LDS tiles, stride 65 (r9 verified)
    const int idx = b - PREP_Q_BLOCKS - PREP_E_BLOCKS;
    const int n0 = (idx & 127) * 64;
    const int k0 = (idx >> 7) * 64;
    const int r = tid >> 4;
    const int c4 = tid & 15;
    #pragma unroll
    for (int p = 0; p < 4; p++) {
        const int row = p * 16 + r;
        const float4 v = *(const float4*)(E + (size_t)(n0 + row) * KDIM + k0 + c4 * 4);
        tile[row][c4 * 4 + 0] = v.x;
        tile[row][c4 * 4 + 1] = v.y;
        tile[row][c4 * 4 + 2] = v.z;
        tile[row][c4 * 4 + 3] = v.w;
    }
    __syncthreads();
    #pragma unroll
    for (int p = 0; p < 4; p++) {
        const int d = p * 16 + r;
        float4 o;
        o.x = tile[c4 * 4 + 0][d];
        o.y = tile[c4 * 4 + 1][d];
        o.z = tile[c4 * 4 + 2][d];
        o.w = tile[c4 * 4 + 3][d];
        *(float4*)(ET + (size_t)(k0 + d) * N_CODES + n0 + c4 * 4) = o;
    }
}

// ---------------------------------------------------------------------------
// MFMA approx-distance + packed-u32 top-2 partials, r15:
// r10's verified DOUBLE-buffered structure (48 KB LDS, one barrier/iter,
// measured 103.5 us at 2 blocks/CU) with __launch_bounds__(256,3):
// 48 KB x 3 = 144 KB <= 160 -> THREE blocks/CU. The untested axis after
// r10/r11/r12 all tied at ~103 is TLP: a third block's waves cover the other
// blocks' barrier-drain windows (m114 cross-block overlap mechanism).
//  * staging via global_load_lds w=16, linear LDS dest + PRE-SWIZZLED global
//    source slot g=(lane&3)^((lane>>3)&3); read swizzle qd^((c>>1)&3)
//    (both-sides involution, verified r10).
// d = fmaf(acc, -2^-19, e_sq + 8); key = (bits & 0xFFFFFF00) | local_n.
// ---------------------------------------------------------------------------
union SMemU {
    struct { _Float16 q[2][BM * TS]; _Float16 e[2][BN * TS]; } t;   // 16 KB + 32 KB
    struct { unsigned k1[BM][2]; unsigned k2[BM][2]; } red;
};

__device__ __forceinline__ void gl_lds16(const void* g, void* lds) {
    __builtin_amdgcn_global_load_lds(
        (const __attribute__((address_space(1))) unsigned*)g,
        (__attribute__((address_space(3))) unsigned*)lds, 16, 0, 0);
}

__global__ __launch_bounds__(256, 3)
void mfma_top2_kernel(const _Float16* __restrict__ Qh, const _Float16* __restrict__ Eh,
                      const float* __restrict__ esq,
                      unsigned* __restrict__ k1s, unsigned* __restrict__ k2s) {
    __shared__ SMemU sm;
    const int tid = threadIdx.x;
    const int m0 = blockIdx.x * BM;
    const int n0 = blockIdx.y * BN;
    const int w = tid >> 6, lane = tid & 63;
    const int wm = w >> 1, wn = w & 1;          // 2x2 wave grid: 64 rows x 128 cols each
    const int qd = lane >> 4, c = lane & 15;

    // staging geometry: one wave-issue = 64 lanes x 16 B = 16 rows of TS=32 halfs.
    const int lrow = lane >> 2;
    const int gsw = (lane & 3) ^ ((lane >> 3) & 3);   // == (lane&3) ^ ((row>>1)&3)
    const _Float16* qsrc = Qh + (size_t)(m0 + w * 32 + lrow) * KDIM + gsw * 8;
    const _Float16* esrc = Eh + (size_t)(n0 + w * 64 + lrow) * KDIM + gsw * 8;

    f32x4 acc[4][8];
    const f32x4 zero = {0.f, 0.f, 0.f, 0.f};
    #pragma unroll
    for (int mt = 0; mt < 4; mt++)
        #pragma unroll
        for (int nt = 0; nt < 8; nt++) acc[mt][nt] = zero;

    // per wave: 2 Q issues (rows w*32..+31) + 4 E issues (rows w*64..+63)
    #define STAGE(buf, kofs) do {                                                  \
        _Float16* qdst = sm.t.q[buf] + w * 1024;                                   \
        _Float16* edst = sm.t.e[buf] + w * 2048;                                   \
        gl_lds16(qsrc + (kofs),             qdst);                                 \
        gl_lds16(qsrc + 16 * KDIM + (kofs), qdst + 512);                           \
        gl_lds16(esrc + (kofs),             edst);                                 \
        gl_lds16(esrc + 16 * KDIM + (kofs), edst + 512);                           \
        gl_lds16(esrc + 32 * KDIM + (kofs), edst + 1024);                          \
        gl_lds16(esrc + 48 * KDIM + (kofs), edst + 1536);                          \
    } while (0)

    STAGE(0, 0);
    __syncthreads();                     // compiler emits vmcnt(0) before barrier

    const int csw = (c >> 1) & 3;        // read-side swizzle == (row>>1)&3 for row=16a+c

    for (int ki = 0; ki < NK; ki++) {
        if (ki + 1 < NK) STAGE((ki + 1) & 1, (ki + 1) * BK);   // prefetch next buffer
        const _Float16* bq = sm.t.q[ki & 1];
        const _Float16* be = sm.t.e[ki & 1];
        half8 qa[4];
        #pragma unroll
        for (int mt = 0; mt < 4; mt++)
            qa[mt] = *(const half8*)(bq + (wm * 64 + mt * 16 + c) * TS + (qd ^ csw) * 8);
        #pragma unroll
        for (int nt = 0; nt < 8; nt++) {
            const half8 eh = *(const half8*)(be + (wn * 128 + nt * 16 + c) * TS + (qd ^ csw) * 8);
            #pragma unroll
            for (int mt = 0; mt < 4; mt++)
                acc[mt][nt] = __builtin_amdgcn_mfma_f32_16x16x32_f16(qa[mt], eh, acc[mt][nt], 0, 0, 0);
        }
        if (ki + 1 < NK) __syncthreads();   // single barrier per iteration
    }
    #undef STAGE

    // ---- epilogue: packed top-2 (verified r7-r14; 8-bit local index) ----
    float es8[8];
    #pragma unroll
    for (int nt = 0; nt < 8; nt++) es8[nt] = esq[n0 + wn * 128 + nt * 16 + c] + 8.0f;

    unsigned k1[16], k2[16];
    #pragma unroll
    for (int i = 0; i < 16; i++) { k1[i] = 0xFFFFFFFFu; k2[i] = 0xFFFFFFFFu; }

    #pragma unroll
    for (int mt = 0; mt < 4; mt++)
        #pragma unroll
        for (int nt = 0; nt < 8; nt++) {
            const unsigned nl = (unsigned)(wn * 128 + nt * 16 + c);
            #pragma unroll
            for (int r = 0; r < 4; r++) {
                const int i = mt * 4 + r;
                const float d = fmaf(acc[mt][nt][r], -INV_PROD, es8[nt]);
                const unsigned k = (__float_as_uint(d) & 0xFFFFFF00u) | nl;
                const unsigned t = min(k1[i], k);
                k2[i] = min(k2[i], max(k1[i], k));
                k1[i] = t;
            }
        }
    #pragma unroll
    for (int s = 1; s < 16; s <<= 1) {
        #pragma unroll
        for (int i = 0; i < 16; i++) {
            const unsigned ok1 = (unsigned)__shfl_xor((int)k1[i], s, 64);
            const unsigned ok2 = (unsigned)__shfl_xor((int)k2[i], s, 64);
            const unsigned t = min(k1[i], ok1);
            k2[i] = min(min(k2[i], ok2), max(k1[i], ok1));
            k1[i] = t;
        }
    }
    __syncthreads();
    if (c == 0) {
        #pragma unroll
        for (int mt = 0; mt < 4; mt++)
            #pragma unroll
            for (int r = 0; r < 4; r++) {
                const int ml = wm * 64 + mt * 16 + qd * 4 + r;
                sm.red.k1[ml][wn] = k1[mt * 4 + r];
                sm.red.k2[ml][wn] = k2[mt * 4 + r];
            }
    }
    __syncthreads();
    if (tid < BM) {
        const unsigned a1 = sm.red.k1[tid][0], b1 = sm.red.k1[tid][1];
        const unsigned a2 = sm.red.k2[tid][0], b2 = sm.red.k2[tid][1];
        const size_t o = (size_t)(m0 + tid) * NB + blockIdx.y;
        k1s[o] = min(a1, b1);
        k2s[o] = min(min(a2, b2), max(a1, b1));
    }
}

// ---------------------------------------------------------------------------
// Fused finalize + refine (r15). One wave per query:
//  * merge NB=32 packed partials (unsigned-key domain, sentinel-safe);
//  * safe gap -> emit; narrow gap -> INLINE candidate-block-pruned exact scan
//    (same bound as r14: true argmin's block has float(k1s[b]) < v1+MARGIN;
//    bit-exact ascending-k fmaf chains; two-step-rounded distance; lowest-
//    index tie-break). No fcount/flist, no atomics, no block syncs in the
//    divergent path (per-wave LDS row only).
// ---------------------------------------------------------------------------
__global__ __launch_bounds__(256, 4)
void finalize_refine_kernel(const float* __restrict__ Q, const float* __restrict__ E,
                            const float* __restrict__ ET,
                            const float* __restrict__ qsq, const float* __restrict__ esq,
                            const unsigned* __restrict__ k1s, const unsigned* __restrict__ k2s,
                            float* __restrict__ ws_loss, float* __restrict__ out) {
    __shared__ float qs[4][KDIM];        // per-wave private row (no cross-wave sync)
    const int w = threadIdx.x >> 6;
    const int lane = threadIdx.x & 63;
    const int q = blockIdx.x * 4 + w;

    unsigned d1 = 0xFFFFFF00u;           // sentinel (max positive-float bits, idx-stripped)
    unsigned d2 = 0xFFFFFF00u;
    unsigned myk1 = 0xFFFFFF00u;         // this lane's block-min key (for candidate mask)
    int gi = 0x7FFFFFFF;
    if (lane < NB) {
        const unsigned k1 = k1s[(size_t)q * NB + lane];
        const unsigned k2 = k2s[(size_t)q * NB + lane];
        myk1 = k1 & 0xFFFFFF00u;
        d1 = myk1;
        gi = lane * BN + (int)(k1 & 255u);
        d2 = k2 & 0xFFFFFF00u;
    }
    #pragma unroll
    for (int s = 1; s < 64; s <<= 1) {
        const unsigned od1 = (unsigned)__shfl_xor((int)d1, s, 64);
        const int      ogi = __shfl_xor(gi, s, 64);
        const unsigned od2 = (unsigned)__shfl_xor((int)d2, s, 64);
        const unsigned nd2 = min(min(d2, od2), max(d1, od1));
        const bool take = (od1 < d1) || (od1 == d1 && ogi < gi);
        d1 = take ? od1 : d1;
        gi = take ? ogi : gi;
        d2 = nd2;
    }

    const float4 qv = *(const float4*)(Q + (size_t)q * KDIM + lane * 4);

    if ((__uint_as_float(d2) - __uint_as_float(d1)) < MARGIN) {
        // ---- inline pruned exact refine (bound verified r14-design) ----
        const float thr = __uint_as_float(d1) + MARGIN;
        const bool cand = (lane < NB) && (__uint_as_float(myk1) < thr);
        unsigned cmask = (unsigned)__ballot(cand);   // bits 0..31 (lanes>=NB are 0)
        *(float4*)&qs[w][lane * 4] = qv;             // wave-private LDS row
        const float qsv = qsq[q];
        float bv = FLT_MAX;
        int   bi = 0x7fffffff;
        while (cmask) {
            const int cb = __builtin_ctz(cmask);
            cmask &= cmask - 1;
            const int nb4 = cb * BN + lane * 4;      // 64 lanes x 4 codes (float4 cols)
            float a0 = 0.f, a1 = 0.f, a2 = 0.f, a3 = 0.f;
            for (int k = 0; k < KDIM; k++) {         // bit-exact ascending-k fmaf chains
                const float qk = qs[w][k];
                const float4 ev = *(const float4*)(ET + (size_t)k * N_CODES + nb4);
                a0 = fmaf(qk, ev.x, a0);
                a1 = fmaf(qk, ev.y, a1);
                a2 = fmaf(qk, ev.z, a2);
                a3 = fmaf(qk, ev.w, a3);
            }
            const float av[4] = {a0, a1, a2, a3};
            #pragma unroll
            for (int j = 0; j < 4; j++) {
                float d;
                {
                    #pragma clang fp contract(off)
                    const float t1 = qsv + esq[nb4 + j];
                    d = t1 - 2.0f * av[j];
                }
                if (d < bv || (d == bv && nb4 + j < bi)) { bv = d; bi = nb4 + j; }
            }
        }
        #pragma unroll
        for (int s = 1; s < 64; s <<= 1) {
            const float ov = __shfl_xor(bv, s, 64);
            const int   oi = __shfl_xor(bi, s, 64);
            if (ov < bv || (ov == bv && oi < bi)) { bv = ov; bi = oi; }
        }
        gi = bi;
    }

    // ---- common emit path (identical numerics to r14's two paths) ----
    if (lane == 0) out[q] = (float)gi;
    const float4 ev = *(const float4*)(E + (size_t)gi * KDIM + lane * 4);
    float4 st;
    {
        #pragma clang fp contract(off)
        st.x = qv.x + (ev.x - qv.x);
        st.y = qv.y + (ev.y - qv.y);
        st.z = qv.z + (ev.z - qv.z);
        st.w = qv.w + (ev.w - qv.w);
    }
    *(float4*)(out + M_TOTAL + (size_t)q * KDIM + lane * 4) = st;

    const float dx = qv.x - ev.x, dy = qv.y - ev.y, dz = qv.z - ev.z, dw = qv.w - ev.w;
    float s = dx * dx + dy * dy + dz * dz + dw * dw;
    #pragma unroll
    for (int off = 32; off > 0; off >>= 1) s += __shfl_down(s, off);
    if (lane == 0) ws_loss[q] = s;
}

// ---------------------------------------------------------------------------
// Loss reduction: sum ws_loss[0..M), scale, one atomic per block (32 total).
// ---------------------------------------------------------------------------
__global__ void loss_reduce_kernel(const float* __restrict__ ws_loss, float* __restrict__ out) {
    const int tid = threadIdx.x;
    float s = 0.f;
    for (int i = blockIdx.x * 256 + tid; i < M_TOTAL; i += LR_BLOCKS * 256)
        s += ws_loss[i];
    #pragma unroll
    for (int off = 32; off > 0; off >>= 1) s += __shfl_down(s, off);
    __shared__ float ws[4];
    if ((tid & 63) == 0) ws[tid >> 6] = s;
    __syncthreads();
    if (tid == 0) {
        const float tot = (ws[0] + ws[1]) + (ws[2] + ws[3]);
        atomicAdd(out + M_TOTAL + (size_t)M_TOTAL * KDIM,
                  tot * (1.25f / (float)((size_t)M_TOTAL * KDIM)));
    }
}

extern "C" void kernel_launch(void* const* d_in, const int* in_sizes, int n_in,
                              void* d_out, int out_size, void* d_ws, size_t ws_size,
                              hipStream_t stream) {
    const float* Q = (const float*)d_in[0];   // [16,1024,256] fp32
    const float* E = (const float*)d_in[1];   // [8192,256] fp32
    float* out = (float*)d_out;               // [16384 idx][4194304 quantized][1 loss]

    char* ws = (char*)d_ws;
    _Float16* Qh  = (_Float16*)(ws);                                 // 0..8 MB
    _Float16* Eh  = (_Float16*)(ws + (size_t)8  * 1024 * 1024);      // 8..12 MB
    float* qsq    = (float*)   (ws + (size_t)12 * 1024 * 1024);      // 64 KB
    float* esq    = qsq + M_TOTAL;                                   // 32 KB
    unsigned* k1s = (unsigned*)(ws + (size_t)13 * 1024 * 1024);      // 2 MB (NB=32)
    unsigned* k2s = (unsigned*)(ws + (size_t)17 * 1024 * 1024);      // 2 MB
    float* ws_loss= (float*)   (ws + (size_t)25 * 1024 * 1024 + 512 * 1024);  // 64 KB
    float* ET     = (float*)   (ws + (size_t)26 * 1024 * 1024);      // 8 MB
    float* loss_slot = out + M_TOTAL + (size_t)M_TOTAL * KDIM;

    prep_fused_kernel<<<PREP_Q_BLOCKS + PREP_E_BLOCKS + TR_BLOCKS, 256, 0, stream>>>(
        Q, E, Qh, Eh, qsq, esq, ET, loss_slot);

    mfma_top2_kernel<<<dim3(M_TOTAL / BM, N_CODES / BN), 256, 0, stream>>>(
        Qh, Eh, esq, k1s, k2s);

    finalize_refine_kernel<<<M_TOTAL / 4, 256, 0, stream>>>(
        Q, E, ET, qsq, esq, k1s, k2s, ws_loss, out);

    loss_reduce_kernel<<<LR_BLOCKS, 256, 0, stream>>>(ws_loss, out);
}

// Round 15
// 209.386 us; speedup vs baseline: 1.6377x; 1.6377x over previous
//
#include <hip/hip_runtime.h>
#include <float.h>

typedef _Float16 half8 __attribute__((ext_vector_type(8)));
typedef _Float16 half4v __attribute__((ext_vector_type(4)));
typedef float f32x4 __attribute__((ext_vector_type(4)));

#define M_TOTAL 16384
#define N_CODES 8192
#define KDIM    256
#define BM 128
#define BN 256
#define BK 32
#define NK (KDIM / BK)      // 8 k-iterations
#define NB (N_CODES / BN)   // 32 partials per query
#define TS 32               // LDS tile k-stride in halfs
#define MARGIN 3.6e-3f      // >= 2*(fp16-approx err + 8-bit key truncation)
#define SQ_SCALE 512.0f
#define SE_SCALE 2048.0f
#define INV_PROD 1.9073486328125e-06f   // 2/(512*2048) = 2^-19, exact
#define LR_BLOCKS 32         // loss_reduce grid

// grid split for fused prep kernel
#define PREP_Q_BLOCKS (M_TOTAL / 4)                 // 4096
#define PREP_E_BLOCKS (N_CODES / 4)                 // 2048
#define TR_BLOCKS ((N_CODES / 64) * (KDIM / 64))    // 512

// ---------------------------------------------------------------------------
// prep body: fp32 -> fp16 (exact pow2 scale) + numpy-bit-exact sumsq (r7-r9).
// ---------------------------------------------------------------------------
__device__ __forceinline__ void prep_body(const float* __restrict__ src,
                                          _Float16* __restrict__ dst,
                                          float* __restrict__ sq, float scale,
                                          int row0, int tid) {
    {   // convert
        const int r = row0 + (tid >> 6);
        const int e4 = tid & 63;
        const float4 v = *(const float4*)(src + (size_t)r * KDIM + e4 * 4);
        const half4v h = {(_Float16)(v.x * scale), (_Float16)(v.y * scale),
                          (_Float16)(v.z * scale), (_Float16)(v.w * scale)};
        ((half4v*)(dst + (size_t)r * KDIM))[e4] = h;
    }
    if (tid < 64) {   // np-bit-exact sumsq, 4 rows on wave 0
        const int grp = tid >> 4;
        const int sub = tid & 15;
        const int row = row0 + grp;
        const float* p = src + (size_t)row * KDIM + (sub >> 3) * 128 + (sub & 7);
        float r;
        {
            #pragma clang fp contract(off)
            float v = p[0];
            r = v * v;
            #pragma unroll
            for (int k = 1; k < 16; k++) { const float w = p[k * 8]; r = r + w * w; }
        }
        const float t1 = r  + __shfl_xor(r,  1, 64);
        const float t2 = t1 + __shfl_xor(t1, 2, 64);
        const float t3 = t2 + __shfl_xor(t2, 4, 64);
        const float t4 = t3 + __shfl_xor(t3, 8, 64);
        if (sub == 0) sq[row] = t4;
    }
}

// ---------------------------------------------------------------------------
// Fused prep: prep(Q) + prep(E) + E-transpose in ONE dispatch.
// Block 0 zeroes the loss accumulator.
// ---------------------------------------------------------------------------
__global__ void prep_fused_kernel(const float* __restrict__ Q, const float* __restrict__ E,
                                  _Float16* __restrict__ Qh, _Float16* __restrict__ Eh,
                                  float* __restrict__ qsq, float* __restrict__ esq,
                                  float* __restrict__ ET, float* __restrict__ loss_slot) {
    __shared__ float tile[64][65];
    const int tid = threadIdx.x;
    const int b = blockIdx.x;
    if (b == 0 && tid == 0) *loss_slot = 0.f;
    if (b < PREP_Q_BLOCKS) {
        prep_body(Q, Qh, qsq, SQ_SCALE, b * 4, tid);
        return;
    }
    if (b < PREP_Q_BLOCKS + PREP_E_BLOCKS) {
        prep_body(E, Eh, esq, SE_SCALE, (b - PREP_Q_BLOCKS) * 4, tid);
        return;
    }
    // transpose: ET[k][n] = E[n][k], 64x64 LDS tiles, stride 65 (r9 verified)
    const int idx = b - PREP_Q_BLOCKS - PREP_E_BLOCKS;
    const int n0 = (idx & 127) * 64;
    const int k0 = (idx >> 7) * 64;
    const int r = tid >> 4;
    const int c4 = tid & 15;
    #pragma unroll
    for (int p = 0; p < 4; p++) {
        const int row = p * 16 + r;
        const float4 v = *(const float4*)(E + (size_t)(n0 + row) * KDIM + k0 + c4 * 4);
        tile[row][c4 * 4 + 0] = v.x;
        tile[row][c4 * 4 + 1] = v.y;
        tile[row][c4 * 4 + 2] = v.z;
        tile[row][c4 * 4 + 3] = v.w;
    }
    __syncthreads();
    #pragma unroll
    for (int p = 0; p < 4; p++) {
        const int d = p * 16 + r;
        float4 o;
        o.x = tile[c4 * 4 + 0][d];
        o.y = tile[c4 * 4 + 1][d];
        o.z = tile[c4 * 4 + 2][d];
        o.w = tile[c4 * 4 + 3][d];
        *(float4*)(ET + (size_t)(k0 + d) * N_CODES + n0 + c4 * 4) = o;
    }
}

// ---------------------------------------------------------------------------
// MFMA approx-distance + packed-u32 top-2 partials (r11 VERBATIM — measured
// 101.5 us in r14; r15's launch_bounds(256,3) regression reverted: it forced
// VGPR 104->84 and spilled the 128-reg accumulator to scratch, FETCH 255 MB /
// WRITE 584 MB, 235 us. NEVER bound waves below acc-array VGPR needs.)
//  * T4 counted-vmcnt pipeline: TRIPLE-buffered LDS, 12 global_load_lds in
//    flight, s_barrier + s_waitcnt vmcnt(6), never 0 mid-loop.
//  * T5 s_setprio(1) around the MFMA cluster.
//  * staging via global_load_lds w=16, linear LDS dest + PRE-SWIZZLED global
//    source slot g=(lane&3)^((lane>>3)&3); read swizzle qd^((c>>1)&3).
// d = fmaf(acc, -2^-19, e_sq + 8); key = (bits & 0xFFFFFF00) | local_n.
// ---------------------------------------------------------------------------
union SMemU {
    struct { _Float16 q[3][BM * TS]; _Float16 e[3][BN * TS]; } t;   // 24 KB + 48 KB
    struct { unsigned k1[BM][2]; unsigned k2[BM][2]; } red;
};

__device__ __forceinline__ void gl_lds16(const void* g, void* lds) {
    __builtin_amdgcn_global_load_lds(
        (const __attribute__((address_space(1))) unsigned*)g,
        (__attribute__((address_space(3))) unsigned*)lds, 16, 0, 0);
}

__global__ __launch_bounds__(256, 2)
void mfma_top2_kernel(const _Float16* __restrict__ Qh, const _Float16* __restrict__ Eh,
                      const float* __restrict__ esq,
                      unsigned* __restrict__ k1s, unsigned* __restrict__ k2s) {
    __shared__ SMemU sm;
    const int tid = threadIdx.x;
    const int m0 = blockIdx.x * BM;
    const int n0 = blockIdx.y * BN;
    const int w = tid >> 6, lane = tid & 63;
    const int wm = w >> 1, wn = w & 1;          // 2x2 wave grid: 64 rows x 128 cols each
    const int qd = lane >> 4, c = lane & 15;

    // staging geometry: one wave-issue = 64 lanes x 16 B = 16 rows of TS=32 halfs.
    const int lrow = lane >> 2;
    const int gsw = (lane & 3) ^ ((lane >> 3) & 3);   // == (lane&3) ^ ((row>>1)&3)
    const _Float16* qsrc = Qh + (size_t)(m0 + w * 32 + lrow) * KDIM + gsw * 8;
    const _Float16* esrc = Eh + (size_t)(n0 + w * 64 + lrow) * KDIM + gsw * 8;

    f32x4 acc[4][8];
    const f32x4 zero = {0.f, 0.f, 0.f, 0.f};
    #pragma unroll
    for (int mt = 0; mt < 4; mt++)
        #pragma unroll
        for (int nt = 0; nt < 8; nt++) acc[mt][nt] = zero;

    // per wave: 2 Q issues + 4 E issues = 6 x 1 KB  (vmcnt granularity = 6)
    #define STAGE(buf, kofs) do {                                                  \
        _Float16* qdst = sm.t.q[buf] + w * 1024;                                   \
        _Float16* edst = sm.t.e[buf] + w * 2048;                                   \
        gl_lds16(qsrc + (kofs),             qdst);                                 \
        gl_lds16(qsrc + 16 * KDIM + (kofs), qdst + 512);                           \
        gl_lds16(esrc + (kofs),             edst);                                 \
        gl_lds16(esrc + 16 * KDIM + (kofs), edst + 512);                           \
        gl_lds16(esrc + 32 * KDIM + (kofs), edst + 1024);                          \
        gl_lds16(esrc + 48 * KDIM + (kofs), edst + 1536);                          \
    } while (0)

    // prologue: fill 3-deep pipeline (18 loads), wait only tile0 (12 left in flight)
    STAGE(0, 0);
    STAGE(1, BK);
    STAGE(2, 2 * BK);
    asm volatile("s_waitcnt vmcnt(12)" ::: "memory");
    __builtin_amdgcn_s_barrier();

    const int csw = (c >> 1) & 3;        // read-side swizzle == (row>>1)&3 for row=16a+c

    #pragma unroll
    for (int ki = 0; ki < NK; ki++) {
        const int buf = ki % 3;
        const _Float16* bq = sm.t.q[buf];
        const _Float16* be = sm.t.e[buf];
        half8 qa[4];
        #pragma unroll
        for (int mt = 0; mt < 4; mt++)
            qa[mt] = *(const half8*)(bq + (wm * 64 + mt * 16 + c) * TS + (qd ^ csw) * 8);
        __builtin_amdgcn_s_setprio(1);
        #pragma unroll
        for (int nt = 0; nt < 8; nt++) {
            const half8 eh = *(const half8*)(be + (wn * 128 + nt * 16 + c) * TS + (qd ^ csw) * 8);
            #pragma unroll
            for (int mt = 0; mt < 4; mt++)
                acc[mt][nt] = __builtin_amdgcn_mfma_f32_16x16x32_f16(qa[mt], eh, acc[mt][nt], 0, 0, 0);
        }
        __builtin_amdgcn_s_setprio(0);
        if (ki == NK - 1) break;          // epilogue __syncthreads covers the rest
        // guard tile ki+1: its 6 loads are the oldest outstanding; tile ki+2's
        // 6 may stay in flight (counted wait — never drain to 0 mid-loop).
        if (ki <= NK - 3) { asm volatile("s_waitcnt vmcnt(6)" ::: "memory"); }
        else              { asm volatile("s_waitcnt vmcnt(0)" ::: "memory"); }
        __builtin_amdgcn_s_barrier();     // all waves: done reading buf, tile ki+1 landed
        if (ki + 3 < NK) STAGE(buf, (ki + 3) * BK);   // overwrite just-consumed buffer
    }
    #undef STAGE

    // ---- epilogue: packed top-2 (verified r7-r14; 8-bit local index) ----
    float es8[8];
    #pragma unroll
    for (int nt = 0; nt < 8; nt++) es8[nt] = esq[n0 + wn * 128 + nt * 16 + c] + 8.0f;

    unsigned k1[16], k2[16];
    #pragma unroll
    for (int i = 0; i < 16; i++) { k1[i] = 0xFFFFFFFFu; k2[i] = 0xFFFFFFFFu; }

    #pragma unroll
    for (int mt = 0; mt < 4; mt++)
        #pragma unroll
        for (int nt = 0; nt < 8; nt++) {
            const unsigned nl = (unsigned)(wn * 128 + nt * 16 + c);
            #pragma unroll
            for (int r = 0; r < 4; r++) {
                const int i = mt * 4 + r;
                const float d = fmaf(acc[mt][nt][r], -INV_PROD, es8[nt]);
                const unsigned k = (__float_as_uint(d) & 0xFFFFFF00u) | nl;
                const unsigned t = min(k1[i], k);
                k2[i] = min(k2[i], max(k1[i], k));
                k1[i] = t;
            }
        }
    #pragma unroll
    for (int s = 1; s < 16; s <<= 1) {
        #pragma unroll
        for (int i = 0; i < 16; i++) {
            const unsigned ok1 = (unsigned)__shfl_xor((int)k1[i], s, 64);
            const unsigned ok2 = (unsigned)__shfl_xor((int)k2[i], s, 64);
            const unsigned t = min(k1[i], ok1);
            k2[i] = min(min(k2[i], ok2), max(k1[i], ok1));
            k1[i] = t;
        }
    }
    __syncthreads();
    if (c == 0) {
        #pragma unroll
        for (int mt = 0; mt < 4; mt++)
            #pragma unroll
            for (int r = 0; r < 4; r++) {
                const int ml = wm * 64 + mt * 16 + qd * 4 + r;
                sm.red.k1[ml][wn] = k1[mt * 4 + r];
                sm.red.k2[ml][wn] = k2[mt * 4 + r];
            }
    }
    __syncthreads();
    if (tid < BM) {
        const unsigned a1 = sm.red.k1[tid][0], b1 = sm.red.k1[tid][1];
        const unsigned a2 = sm.red.k2[tid][0], b2 = sm.red.k2[tid][1];
        const size_t o = (size_t)(m0 + tid) * NB + blockIdx.y;
        k1s[o] = min(a1, b1);
        k2s[o] = min(min(a2, b2), max(a1, b1));
    }
}

// ---------------------------------------------------------------------------
// Fused finalize + refine (r15, validated: passed absmax 0.0). One wave per
// query: merge NB=32 packed partials; safe gap -> emit; narrow gap -> INLINE
// candidate-block-pruned exact scan (bound: true argmin's block satisfies
// float(k1s[b]) < v1+MARGIN; bit-exact ascending-k fmaf chains; two-step-
// rounded distance; lowest-index tie-break). No atomics, no block syncs in
// the divergent path (per-wave LDS row only).
// ---------------------------------------------------------------------------
__global__ __launch_bounds__(256, 4)
void finalize_refine_kernel(const float* __restrict__ Q, const float* __restrict__ E,
                            const float* __restrict__ ET,
                            const float* __restrict__ qsq, const float* __restrict__ esq,
                            const unsigned* __restrict__ k1s, const unsigned* __restrict__ k2s,
                            float* __restrict__ ws_loss, float* __restrict__ out) {
    __shared__ float qs[4][KDIM];        // per-wave private row (no cross-wave sync)
    const int w = threadIdx.x >> 6;
    const int lane = threadIdx.x & 63;
    const int q = blockIdx.x * 4 + w;

    unsigned d1 = 0xFFFFFF00u;           // sentinel (max positive-float bits, idx-stripped)
    unsigned d2 = 0xFFFFFF00u;
    unsigned myk1 = 0xFFFFFF00u;         // this lane's block-min key (for candidate mask)
    int gi = 0x7FFFFFFF;
    if (lane < NB) {
        const unsigned k1 = k1s[(size_t)q * NB + lane];
        const unsigned k2 = k2s[(size_t)q * NB + lane];
        myk1 = k1 & 0xFFFFFF00u;
        d1 = myk1;
        gi = lane * BN + (int)(k1 & 255u);
        d2 = k2 & 0xFFFFFF00u;
    }
    #pragma unroll
    for (int s = 1; s < 64; s <<= 1) {
        const unsigned od1 = (unsigned)__shfl_xor((int)d1, s, 64);
        const int      ogi = __shfl_xor(gi, s, 64);
        const unsigned od2 = (unsigned)__shfl_xor((int)d2, s, 64);
        const unsigned nd2 = min(min(d2, od2), max(d1, od1));
        const bool take = (od1 < d1) || (od1 == d1 && ogi < gi);
        d1 = take ? od1 : d1;
        gi = take ? ogi : gi;
        d2 = nd2;
    }

    const float4 qv = *(const float4*)(Q + (size_t)q * KDIM + lane * 4);

    if ((__uint_as_float(d2) - __uint_as_float(d1)) < MARGIN) {
        // ---- inline pruned exact refine ----
        const float thr = __uint_as_float(d1) + MARGIN;
        const bool cand = (lane < NB) && (__uint_as_float(myk1) < thr);
        unsigned cmask = (unsigned)__ballot(cand);   // bits 0..31 (lanes>=NB are 0)
        *(float4*)&qs[w][lane * 4] = qv;             // wave-private LDS row
        const float qsv = qsq[q];
        float bv = FLT_MAX;
        int   bi = 0x7fffffff;
        while (cmask) {
            const int cb = __builtin_ctz(cmask);
            cmask &= cmask - 1;
            const int nb4 = cb * BN + lane * 4;      // 64 lanes x 4 codes (float4 cols)
            float a0 = 0.f, a1 = 0.f, a2 = 0.f, a3 = 0.f;
            for (int k = 0; k < KDIM; k++) {         // bit-exact ascending-k fmaf chains
                const float qk = qs[w][k];
                const float4 ev = *(const float4*)(ET + (size_t)k * N_CODES + nb4);
                a0 = fmaf(qk, ev.x, a0);
                a1 = fmaf(qk, ev.y, a1);
                a2 = fmaf(qk, ev.z, a2);
                a3 = fmaf(qk, ev.w, a3);
            }
            const float av[4] = {a0, a1, a2, a3};
            #pragma unroll
            for (int j = 0; j < 4; j++) {
                float d;
                {
                    #pragma clang fp contract(off)
                    const float t1 = qsv + esq[nb4 + j];
                    d = t1 - 2.0f * av[j];
                }
                if (d < bv || (d == bv && nb4 + j < bi)) { bv = d; bi = nb4 + j; }
            }
        }
        #pragma unroll
        for (int s = 1; s < 64; s <<= 1) {
            const float ov = __shfl_xor(bv, s, 64);
            const int   oi = __shfl_xor(bi, s, 64);
            if (ov < bv || (ov == bv && oi < bi)) { bv = ov; bi = oi; }
        }
        gi = bi;
    }

    // ---- common emit path ----
    if (lane == 0) out[q] = (float)gi;
    const float4 ev = *(const float4*)(E + (size_t)gi * KDIM + lane * 4);
    float4 st;
    {
        #pragma clang fp contract(off)
        st.x = qv.x + (ev.x - qv.x);
        st.y = qv.y + (ev.y - qv.y);
        st.z = qv.z + (ev.z - qv.z);
        st.w = qv.w + (ev.w - qv.w);
    }
    *(float4*)(out + M_TOTAL + (size_t)q * KDIM + lane * 4) = st;

    const float dx = qv.x - ev.x, dy = qv.y - ev.y, dz = qv.z - ev.z, dw = qv.w - ev.w;
    float s = dx * dx + dy * dy + dz * dz + dw * dw;
    #pragma unroll
    for (int off = 32; off > 0; off >>= 1) s += __shfl_down(s, off);
    if (lane == 0) ws_loss[q] = s;
}

// ---------------------------------------------------------------------------
// Loss reduction: sum ws_loss[0..M), scale, one atomic per block (32 total).
// ---------------------------------------------------------------------------
__global__ void loss_reduce_kernel(const float* __restrict__ ws_loss, float* __restrict__ out) {
    const int tid = threadIdx.x;
    float s = 0.f;
    for (int i = blockIdx.x * 256 + tid; i < M_TOTAL; i += LR_BLOCKS * 256)
        s += ws_loss[i];
    #pragma unroll
    for (int off = 32; off > 0; off >>= 1) s += __shfl_down(s, off);
    __shared__ float ws[4];
    if ((tid & 63) == 0) ws[tid >> 6] = s;
    __syncthreads();
    if (tid == 0) {
        const float tot = (ws[0] + ws[1]) + (ws[2] + ws[3]);
        atomicAdd(out + M_TOTAL + (size_t)M_TOTAL * KDIM,
                  tot * (1.25f / (float)((size_t)M_TOTAL * KDIM)));
    }
}

extern "C" void kernel_launch(void* const* d_in, const int* in_sizes, int n_in,
                              void* d_out, int out_size, void* d_ws, size_t ws_size,
                              hipStream_t stream) {
    const float* Q = (const float*)d_in[0];   // [16,1024,256] fp32
    const float* E = (const float*)d_in[1];   // [8192,256] fp32
    float* out = (float*)d_out;               // [16384 idx][4194304 quantized][1 loss]

    char* ws = (char*)d_ws;
    _Float16* Qh  = (_Float16*)(ws);                                 // 0..8 MB
    _Float16* Eh  = (_Float16*)(ws + (size_t)8  * 1024 * 1024);      // 8..12 MB
    float* qsq    = (float*)   (ws + (size_t)12 * 1024 * 1024);      // 64 KB
    float* esq    = qsq + M_TOTAL;                                   // 32 KB
    unsigned* k1s = (unsigned*)(ws + (size_t)13 * 1024 * 1024);      // 2 MB (NB=32)
    unsigned* k2s = (unsigned*)(ws + (size_t)17 * 1024 * 1024);      // 2 MB
    float* ws_loss= (float*)   (ws + (size_t)25 * 1024 * 1024 + 512 * 1024);  // 64 KB
    float* ET     = (float*)   (ws + (size_t)26 * 1024 * 1024);      // 8 MB
    float* loss_slot = out + M_TOTAL + (size_t)M_TOTAL * KDIM;

    prep_fused_kernel<<<PREP_Q_BLOCKS + PREP_E_BLOCKS + TR_BLOCKS, 256, 0, stream>>>(
        Q, E, Qh, Eh, qsq, esq, ET, loss_slot);

    mfma_top2_kernel<<<dim3(M_TOTAL / BM, N_CODES / BN), 256, 0, stream>>>(
        Qh, Eh, esq, k1s, k2s);

    finalize_refine_kernel<<<M_TOTAL / 4, 256, 0, stream>>>(
        Q, E, ET, qsq, esq, k1s, k2s, ws_loss, out);

    loss_reduce_kernel<<<LR_BLOCKS, 256, 0, stream>>>(ws_loss, out);
}